// Round 10
// baseline (412.051 us; speedup 1.0000x reference)
//
#include <hip/hip_runtime.h>

#define NCH 32

typedef __attribute__((ext_vector_type(8))) __bf16 bf16x8;
typedef __attribute__((ext_vector_type(4))) float  f32x4;

union bcast16 { int4 i; bf16x8 h; };

// Split 8 fp32 values into bf16 hi + bf16 lo (residual) fragments.
// ah*bh + al*bh + ah*bl reconstructs the fp32 product to ~2^-16 relative.
static __device__ __forceinline__ void split8(const float* x, bf16x8& hi, bf16x8& lo)
{
#pragma unroll
    for (int e = 0; e < 8; ++e) {
        __bf16 h = (__bf16)x[e];
        hi[e] = h;
        lo[e] = (__bf16)(x[e] - (float)h);
    }
}

static __device__ __forceinline__ void mfma3(
    const bf16x8& ah, const bf16x8& al,
    const bf16x8& wh, const bf16x8& wl, f32x4& acc)
{
    acc = __builtin_amdgcn_mfma_f32_16x16x32_bf16(ah, wh, acc, 0, 0, 0);
    acc = __builtin_amdgcn_mfma_f32_16x16x32_bf16(al, wh, acc, 0, 0, 0);
    acc = __builtin_amdgcn_mfma_f32_16x16x32_bf16(ah, wl, acc, 0, 0, 0);
}

static __device__ __forceinline__ ushort f2bf(float x)
{
    __bf16 b = (__bf16)x;
    return *(const ushort*)&b;
}

// Factorized 1D sparse conv as MFMA GEMM over 16-point tiles — round-2
// structure verbatim; in/out dtypes templated.
// IN_BF16:  input rows are bf16 [n][32]; A fragment = one 16B load, no split.
// !IN_BF16: input rows are fp32 and loaded NON-TEMPORAL via f32x4 ext-vector
//           (feats is read exactly once; keep it from evicting the reused
//           h/idx arrays out of the 256MB L3 — working set h1+h2+h3+idx
//           ~228MB fits L3 only if the one-shot 128MB streams bypass it).
// OUT_BF16: store accumulators as bf16 (RNE); else fp32.
// ZERO_STATS: block 0 zeroes stats[64] at kernel start (consumed by the
// DO_STATS pass two kernel boundaries later -> ordering guaranteed).
// A fragment: lane holds f[row = tb + (lane&15)][c0..c0+7], c0=(lane>>4)*8.
// B fragments (3 taps x 2 halves, hi/lo = fp32-exact weights) in registers.
// C/D: out[tb + (lane>>4)*4 + r][(lane&15) + 16*half].
// Tap 1 is the identity map (offset 0) -> own row, no index load.
// Taps 0/2 behind wave-uniform __any skip (~37% whole-tile skip at 6% occ).
// DO_STATS: fused per-channel sum/sumsq from the fp32 accumulators,
// shuffle+LDS combine, 64 atomicAdds per block.
template<int IN_BF16, int OUT_BF16, int DO_STATS, int ZERO_STATS>
__global__ __launch_bounds__(256) void conv_mfma_kernel(
    const void* __restrict__ fin, const float* __restrict__ W,
    const int* __restrict__ idx, void* __restrict__ outv, int n,
    float* __restrict__ stats)
{
    __shared__ float red[4][4][16];

    if constexpr (ZERO_STATS) {
        if (blockIdx.x == 0 && threadIdx.x < 2 * NCH) stats[threadIdx.x] = 0.f;
    }

    const int lane = threadIdx.x & 63;
    const int wv   = threadIdx.x >> 6;
    const int r16  = lane & 15;
    const int g    = lane >> 4;
    const int c0   = g * 8;

    const float*  ff = (const float*)fin;
    const ushort* fb = (const ushort*)fin;
    float*  of = (float*)outv;
    ushort* ob = (ushort*)outv;

    // B fragments: 3 taps x 2 output halves, hi/lo split (held in VGPRs).
    bf16x8 bh[3][2], bl[3][2];
#pragma unroll
    for (int k = 0; k < 3; ++k) {
#pragma unroll
        for (int h = 0; h < 2; ++h) {
            float w8[8];
#pragma unroll
            for (int e = 0; e < 8; ++e)
                w8[e] = W[k * NCH * NCH + (c0 + e) * NCH + (h * 16 + r16)];
            split8(w8, bh[k][h], bl[k][h]);
        }
    }

    const int ntiles = (n + 15) >> 4;
    const int nw = gridDim.x * 4;
    float s0 = 0.f, q0 = 0.f, s1 = 0.f, q1 = 0.f;

    for (int tile = blockIdx.x * 4 + wv; tile < ntiles; tile += nw) {
        const int tb = tile << 4;
        f32x4 a0 = {0.f, 0.f, 0.f, 0.f};
        f32x4 a1 = {0.f, 0.f, 0.f, 0.f};

        const int  p   = tb + r16;
        const bool pin = (p < n);

        auto dotap = [&](int k, int row, bool v) {
            if constexpr (IN_BF16) {
                int4 raw = *(const int4*)(fb + (size_t)row * NCH + c0);
                if (!v) { raw.x = 0; raw.y = 0; raw.z = 0; raw.w = 0; }
                bcast16 u; u.i = raw;
                a0 = __builtin_amdgcn_mfma_f32_16x16x32_bf16(u.h, bh[k][0], a0, 0, 0, 0);
                a0 = __builtin_amdgcn_mfma_f32_16x16x32_bf16(u.h, bl[k][0], a0, 0, 0, 0);
                a1 = __builtin_amdgcn_mfma_f32_16x16x32_bf16(u.h, bh[k][1], a1, 0, 0, 0);
                a1 = __builtin_amdgcn_mfma_f32_16x16x32_bf16(u.h, bl[k][1], a1, 0, 0, 0);
            } else {
                const f32x4* rp = (const f32x4*)(ff + (size_t)row * NCH + c0);
                f32x4 x0 = __builtin_nontemporal_load(rp);
                f32x4 x1 = __builtin_nontemporal_load(rp + 1);
                float m = v ? 1.f : 0.f;
                float x[8] = {x0.x * m, x0.y * m, x0.z * m, x0.w * m,
                              x1.x * m, x1.y * m, x1.z * m, x1.w * m};
                bf16x8 ah, al;
                split8(x, ah, al);
                mfma3(ah, al, bh[k][0], bl[k][0], a0);
                mfma3(ah, al, bh[k][1], bl[k][1], a1);
            }
        };

        // ---- tap 1: identity (own row) ----
        dotap(1, pin ? p : 0, pin);

        // ---- taps 0 and 2: random gathers ----
#pragma unroll
        for (int t = 0; t < 2; ++t) {
            const int k = t * 2;
            int  i = idx[(size_t)k * n + (pin ? p : 0)];
            bool v = pin && (i < n);
            if (__any(v)) dotap(k, v ? i : 0, v);
        }

        // ---- store C: row = tb + g*4 + r, col = r16 / r16+16 ----
#pragma unroll
        for (int r = 0; r < 4; ++r) {
            int prow = tb + g * 4 + r;
            if (prow < n) {
                if constexpr (OUT_BF16) {
                    ushort* o = ob + (size_t)prow * NCH + r16;
                    o[0]  = f2bf(a0[r]);
                    o[16] = f2bf(a1[r]);
                } else {
                    float* o = of + (size_t)prow * NCH + r16;
                    o[0]  = a0[r];
                    o[16] = a1[r];
                }
            }
        }

        if constexpr (DO_STATS) {
#pragma unroll
            for (int r = 0; r < 4; ++r) {
                s0 += a0[r]; q0 = fmaf(a0[r], a0[r], q0);
                s1 += a1[r]; q1 = fmaf(a1[r], a1[r], q1);
            }
        }
    }

    if constexpr (DO_STATS) {
        // lanes with the same (lane&15) hold the same channel: xor-16/32 reduce
        s0 += __shfl_xor(s0, 16); s0 += __shfl_xor(s0, 32);
        q0 += __shfl_xor(q0, 16); q0 += __shfl_xor(q0, 32);
        s1 += __shfl_xor(s1, 16); s1 += __shfl_xor(s1, 32);
        q1 += __shfl_xor(q1, 16); q1 += __shfl_xor(q1, 32);
        if (lane < 16) {
            red[wv][0][r16] = s0;
            red[wv][1][r16] = q0;
            red[wv][2][r16] = s1;
            red[wv][3][r16] = q1;
        }
        __syncthreads();
        if (threadIdx.x < 64) {
            int vsel = threadIdx.x >> 4;   // 0:sum lo, 1:sq lo, 2:sum hi, 3:sq hi
            int ch   = threadIdx.x & 15;
            float t = red[0][vsel][ch] + red[1][vsel][ch] +
                      red[2][vsel][ch] + red[3][vsel][ch];
            int channel = (vsel & 2) ? (ch + 16) : ch;
            atomicAdd(stats + ((vsel & 1) ? NCH : 0) + channel, t);
        }
    }
}

// BatchNorm (batch stats) + ReLU: read bf16 h3 [n,32], write fp32 out [n,32].
// Out is written exactly once and never re-read -> non-temporal store keeps
// the 128MB stream from evicting the reused h/idx arrays out of L3.
__global__ __launch_bounds__(256) void bn_relu_kernel(
    const ushort* __restrict__ h3, float* __restrict__ out,
    const float* __restrict__ stats,
    const float* __restrict__ gamma, const float* __restrict__ beta, int n)
{
    long tid = (long)blockIdx.x * 256 + threadIdx.x;
    long total4 = (long)n * NCH / 4;
    if (tid >= total4) return;

    int ch0 = ((int)(tid & 7)) * 4;
    float inv_n = 1.f / (float)n;

    ushort4 v = ((const ushort4*)h3)[tid];
    ushort u[4] = {v.x, v.y, v.z, v.w};
    float r[4];
#pragma unroll
    for (int j = 0; j < 4; ++j)
        r[j] = __uint_as_float(((unsigned)u[j]) << 16);

#pragma unroll
    for (int j = 0; j < 4; ++j) {
        int ch = ch0 + j;
        float mean = stats[ch] * inv_n;
        float var = stats[NCH + ch] * inv_n - mean * mean;
        float scale = gamma[ch] * rsqrtf(var + 1e-5f);
        float shift = beta[ch] - mean * scale;
        float o = fmaf(r[j], scale, shift);
        r[j] = o > 0.f ? o : 0.f;
    }
    f32x4 o4 = {r[0], r[1], r[2], r[3]};
    __builtin_nontemporal_store(o4, (f32x4*)out + tid);
}

extern "C" void kernel_launch(void* const* d_in, const int* in_sizes, int n_in,
                              void* d_out, int out_size, void* d_ws, size_t ws_size,
                              hipStream_t stream)
{
    const float* feats = (const float*)d_in[0];
    const float* W1    = (const float*)d_in[1];
    const float* W2    = (const float*)d_in[2];
    const float* W3    = (const float*)d_in[3];
    const float* gamma = (const float*)d_in[4];
    const float* beta  = (const float*)d_in[5];
    const int*   nbr   = (const int*)d_in[6];   // [3 axes][3 taps][n]

    int n = in_sizes[0] / NCH;

    float*  hout = (float*)d_out;                     // final out (fp32)
    ushort* h1   = (ushort*)d_ws;                     // n*32 bf16; h3 reuses it
    ushort* h2   = h1 + (size_t)n * NCH;              // n*32 bf16
    ushort* h3   = h1;                                // h1 dead after conv2
    float*  stats = (float*)(h2 + (size_t)n * NCH);   // 64 floats

    const int cblocks = 2048;   // 8192 waves = full wave capacity at VGPR<=64

    // conv1: axis 2 (z), fp32 feats (nt) -> bf16 h1; block 0 zeroes stats
    conv_mfma_kernel<0, 1, 0, 1><<<cblocks, 256, 0, stream>>>(
        feats, W1, nbr + (size_t)2 * 3 * n, h1, n, stats);
    // conv2: axis 1 (y), bf16 h1 -> bf16 h2
    conv_mfma_kernel<1, 1, 0, 0><<<cblocks, 256, 0, stream>>>(
        h1, W2, nbr + (size_t)1 * 3 * n, h2, n, stats);
    // conv3: axis 0 (x), bf16 h2 -> bf16 h3 (h1's slot), fused sum/sumsq
    conv_mfma_kernel<1, 1, 1, 0><<<cblocks, 256, 0, stream>>>(
        h2, W3, nbr + (size_t)0 * 3 * n, h3, n, stats);

    // BN + ReLU: bf16 h3 -> fp32 d_out (nt store)
    long total4 = (long)n * NCH / 4;
    int nblocks = (int)((total4 + 255) / 256);
    bn_relu_kernel<<<nblocks, 256, 0, stream>>>(h3, hout, stats, gamma, beta, n);
}

// Round 11
// 404.596 us; speedup vs baseline: 1.0184x; 1.0184x over previous
//
#include <hip/hip_runtime.h>

#define NCH 32

typedef __attribute__((ext_vector_type(8))) __bf16 bf16x8;
typedef __attribute__((ext_vector_type(4))) float  f32x4;

union bcast16 { int4 i; bf16x8 h; };

// Split 8 fp32 values into bf16 hi + bf16 lo (residual) fragments.
// ah*bh + al*bh + ah*bl reconstructs the fp32 product to ~2^-16 relative.
static __device__ __forceinline__ void split8(const float* x, bf16x8& hi, bf16x8& lo)
{
#pragma unroll
    for (int e = 0; e < 8; ++e) {
        __bf16 h = (__bf16)x[e];
        hi[e] = h;
        lo[e] = (__bf16)(x[e] - (float)h);
    }
}

static __device__ __forceinline__ void mfma3(
    const bf16x8& ah, const bf16x8& al,
    const bf16x8& wh, const bf16x8& wl, f32x4& acc)
{
    acc = __builtin_amdgcn_mfma_f32_16x16x32_bf16(ah, wh, acc, 0, 0, 0);
    acc = __builtin_amdgcn_mfma_f32_16x16x32_bf16(al, wh, acc, 0, 0, 0);
    acc = __builtin_amdgcn_mfma_f32_16x16x32_bf16(ah, wl, acc, 0, 0, 0);
}

static __device__ __forceinline__ ushort f2bf(float x)
{
    __bf16 b = (__bf16)x;
    return *(const ushort*)&b;
}

// Factorized 1D sparse conv as MFMA GEMM over 16-point tiles — round-2
// structure verbatim; in/out dtypes templated.
// IN_BF16:  input rows are bf16 [n][32]; A fragment = one 16B load, no split.
// !IN_BF16: input rows are fp32 (nt-loaded; read exactly once).
// OUT_BF16: store accumulators as bf16 (RNE); else fp32.
// C-STORE (the round-11 change): the MFMA C layout scatters each lane's 8
// outputs as 2B stores across 4-8 rows (8 fragmented store insts/lane).
// Full tiles now stage the 16x32 bf16 C-tile through a 1KB per-wave LDS
// buffer (wave-synchronous, no barrier) and store it as ONE coalesced 16B
// store per lane. Tail tiles (never taken at n%16==0) use the old path.
// ZERO_STATS: block 0 zeroes stats[64] at kernel start (consumed by the
// DO_STATS pass two kernel boundaries later -> ordering guaranteed).
// A fragment: lane holds f[row = tb + (lane&15)][c0..c0+7], c0=(lane>>4)*8.
// B fragments (3 taps x 2 halves, hi/lo = fp32-exact weights) in registers.
// C/D: out[tb + (lane>>4)*4 + r][(lane&15) + 16*half].
// Tap 1 is the identity map (offset 0) -> own row, no index load.
// Taps 0/2 behind wave-uniform __any skip (~37% whole-tile skip at 6% occ).
// DO_STATS: fused per-channel sum/sumsq from the fp32 accumulators,
// shuffle+LDS combine, 64 atomicAdds per block.
template<int IN_BF16, int OUT_BF16, int DO_STATS, int ZERO_STATS>
__global__ __launch_bounds__(256) void conv_mfma_kernel(
    const void* __restrict__ fin, const float* __restrict__ W,
    const int* __restrict__ idx, void* __restrict__ outv, int n,
    float* __restrict__ stats)
{
    __shared__ float red[4][4][16];
    __shared__ ushort ctile[4][16][NCH];   // per-wave 1KB C staging

    if constexpr (ZERO_STATS) {
        if (blockIdx.x == 0 && threadIdx.x < 2 * NCH) stats[threadIdx.x] = 0.f;
    }

    const int lane = threadIdx.x & 63;
    const int wv   = threadIdx.x >> 6;
    const int r16  = lane & 15;
    const int g    = lane >> 4;
    const int c0   = g * 8;

    const float*  ff = (const float*)fin;
    const ushort* fb = (const ushort*)fin;
    float*  of = (float*)outv;
    ushort* ob = (ushort*)outv;

    // B fragments: 3 taps x 2 output halves, hi/lo split (held in VGPRs).
    bf16x8 bh[3][2], bl[3][2];
#pragma unroll
    for (int k = 0; k < 3; ++k) {
#pragma unroll
        for (int h = 0; h < 2; ++h) {
            float w8[8];
#pragma unroll
            for (int e = 0; e < 8; ++e)
                w8[e] = W[k * NCH * NCH + (c0 + e) * NCH + (h * 16 + r16)];
            split8(w8, bh[k][h], bl[k][h]);
        }
    }

    const int ntiles = (n + 15) >> 4;
    const int nw = gridDim.x * 4;
    float s0 = 0.f, q0 = 0.f, s1 = 0.f, q1 = 0.f;

    for (int tile = blockIdx.x * 4 + wv; tile < ntiles; tile += nw) {
        const int tb = tile << 4;
        f32x4 a0 = {0.f, 0.f, 0.f, 0.f};
        f32x4 a1 = {0.f, 0.f, 0.f, 0.f};

        const int  p   = tb + r16;
        const bool pin = (p < n);

        auto dotap = [&](int k, int row, bool v) {
            if constexpr (IN_BF16) {
                int4 raw = *(const int4*)(fb + (size_t)row * NCH + c0);
                if (!v) { raw.x = 0; raw.y = 0; raw.z = 0; raw.w = 0; }
                bcast16 u; u.i = raw;
                a0 = __builtin_amdgcn_mfma_f32_16x16x32_bf16(u.h, bh[k][0], a0, 0, 0, 0);
                a0 = __builtin_amdgcn_mfma_f32_16x16x32_bf16(u.h, bl[k][0], a0, 0, 0, 0);
                a1 = __builtin_amdgcn_mfma_f32_16x16x32_bf16(u.h, bh[k][1], a1, 0, 0, 0);
                a1 = __builtin_amdgcn_mfma_f32_16x16x32_bf16(u.h, bl[k][1], a1, 0, 0, 0);
            } else {
                const f32x4* rp = (const f32x4*)(ff + (size_t)row * NCH + c0);
                f32x4 x0 = __builtin_nontemporal_load(rp);
                f32x4 x1 = __builtin_nontemporal_load(rp + 1);
                float m = v ? 1.f : 0.f;
                float x[8] = {x0.x * m, x0.y * m, x0.z * m, x0.w * m,
                              x1.x * m, x1.y * m, x1.z * m, x1.w * m};
                bf16x8 ah, al;
                split8(x, ah, al);
                mfma3(ah, al, bh[k][0], bl[k][0], a0);
                mfma3(ah, al, bh[k][1], bl[k][1], a1);
            }
        };

        // ---- tap 1: identity (own row) ----
        dotap(1, pin ? p : 0, pin);

        // ---- taps 0 and 2: random gathers ----
#pragma unroll
        for (int t = 0; t < 2; ++t) {
            const int k = t * 2;
            int  i = idx[(size_t)k * n + (pin ? p : 0)];
            bool v = pin && (i < n);
            if (__any(v)) dotap(k, v ? i : 0, v);
        }

        // ---- store C ----
        if (OUT_BF16 && tb + 16 <= n) {
            // full tile: stage through per-wave LDS, one 16B store per lane
#pragma unroll
            for (int r = 0; r < 4; ++r) {
                ctile[wv][g * 4 + r][r16]      = f2bf(a0[r]);
                ctile[wv][g * 4 + r][r16 + 16] = f2bf(a1[r]);
            }
            // wave-synchronous: same-wave LDS RAW, compiler inserts lgkmcnt
            uint4 rowv = *(const uint4*)((const char*)&ctile[wv][0][0] + lane * 16);
            *(uint4*)(ob + (size_t)tb * NCH + lane * 8) = rowv;
        } else {
#pragma unroll
            for (int r = 0; r < 4; ++r) {
                int prow = tb + g * 4 + r;
                if (prow < n) {
                    if constexpr (OUT_BF16) {
                        ushort* o = ob + (size_t)prow * NCH + r16;
                        o[0]  = f2bf(a0[r]);
                        o[16] = f2bf(a1[r]);
                    } else {
                        float* o = of + (size_t)prow * NCH + r16;
                        o[0]  = a0[r];
                        o[16] = a1[r];
                    }
                }
            }
        }

        if constexpr (DO_STATS) {
#pragma unroll
            for (int r = 0; r < 4; ++r) {
                s0 += a0[r]; q0 = fmaf(a0[r], a0[r], q0);
                s1 += a1[r]; q1 = fmaf(a1[r], a1[r], q1);
            }
        }
    }

    if constexpr (DO_STATS) {
        // lanes with the same (lane&15) hold the same channel: xor-16/32 reduce
        s0 += __shfl_xor(s0, 16); s0 += __shfl_xor(s0, 32);
        q0 += __shfl_xor(q0, 16); q0 += __shfl_xor(q0, 32);
        s1 += __shfl_xor(s1, 16); s1 += __shfl_xor(s1, 32);
        q1 += __shfl_xor(q1, 16); q1 += __shfl_xor(q1, 32);
        if (lane < 16) {
            red[wv][0][r16] = s0;
            red[wv][1][r16] = q0;
            red[wv][2][r16] = s1;
            red[wv][3][r16] = q1;
        }
        __syncthreads();
        if (threadIdx.x < 64) {
            int vsel = threadIdx.x >> 4;   // 0:sum lo, 1:sq lo, 2:sum hi, 3:sq hi
            int ch   = threadIdx.x & 15;
            float t = red[0][vsel][ch] + red[1][vsel][ch] +
                      red[2][vsel][ch] + red[3][vsel][ch];
            int channel = (vsel & 2) ? (ch + 16) : ch;
            atomicAdd(stats + ((vsel & 1) ? NCH : 0) + channel, t);
        }
    }
}

// BatchNorm (batch stats) + ReLU: read bf16 h3 [n,32], write fp32 out [n,32].
__global__ __launch_bounds__(256) void bn_relu_kernel(
    const ushort* __restrict__ h3, float* __restrict__ out,
    const float* __restrict__ stats,
    const float* __restrict__ gamma, const float* __restrict__ beta, int n)
{
    long tid = (long)blockIdx.x * 256 + threadIdx.x;
    long total4 = (long)n * NCH / 4;
    if (tid >= total4) return;

    int ch0 = ((int)(tid & 7)) * 4;
    float inv_n = 1.f / (float)n;

    ushort4 v = ((const ushort4*)h3)[tid];
    ushort u[4] = {v.x, v.y, v.z, v.w};
    float r[4];
#pragma unroll
    for (int j = 0; j < 4; ++j)
        r[j] = __uint_as_float(((unsigned)u[j]) << 16);

#pragma unroll
    for (int j = 0; j < 4; ++j) {
        int ch = ch0 + j;
        float mean = stats[ch] * inv_n;
        float var = stats[NCH + ch] * inv_n - mean * mean;
        float scale = gamma[ch] * rsqrtf(var + 1e-5f);
        float shift = beta[ch] - mean * scale;
        float o = fmaf(r[j], scale, shift);
        r[j] = o > 0.f ? o : 0.f;
    }
    f32x4 o4 = {r[0], r[1], r[2], r[3]};
    __builtin_nontemporal_store(o4, (f32x4*)out + tid);
}

extern "C" void kernel_launch(void* const* d_in, const int* in_sizes, int n_in,
                              void* d_out, int out_size, void* d_ws, size_t ws_size,
                              hipStream_t stream)
{
    const float* feats = (const float*)d_in[0];
    const float* W1    = (const float*)d_in[1];
    const float* W2    = (const float*)d_in[2];
    const float* W3    = (const float*)d_in[3];
    const float* gamma = (const float*)d_in[4];
    const float* beta  = (const float*)d_in[5];
    const int*   nbr   = (const int*)d_in[6];   // [3 axes][3 taps][n]

    int n = in_sizes[0] / NCH;

    float*  hout = (float*)d_out;                     // final out (fp32)
    ushort* h1   = (ushort*)d_ws;                     // n*32 bf16; h3 reuses it
    ushort* h2   = h1 + (size_t)n * NCH;              // n*32 bf16
    ushort* h3   = h1;                                // h1 dead after conv2
    float*  stats = (float*)(h2 + (size_t)n * NCH);   // 64 floats

    const int cblocks = 2048;   // 8192 waves

    // conv1: axis 2 (z), fp32 feats (nt) -> bf16 h1; block 0 zeroes stats
    conv_mfma_kernel<0, 1, 0, 1><<<cblocks, 256, 0, stream>>>(
        feats, W1, nbr + (size_t)2 * 3 * n, h1, n, stats);
    // conv2: axis 1 (y), bf16 h1 -> bf16 h2
    conv_mfma_kernel<1, 1, 0, 0><<<cblocks, 256, 0, stream>>>(
        h1, W2, nbr + (size_t)1 * 3 * n, h2, n, stats);
    // conv3: axis 0 (x), bf16 h2 -> bf16 h3 (h1's slot), fused sum/sumsq
    conv_mfma_kernel<1, 1, 1, 0><<<cblocks, 256, 0, stream>>>(
        h2, W3, nbr + (size_t)0 * 3 * n, h3, n, stats);

    // BN + ReLU: bf16 h3 -> fp32 d_out (nt store)
    long total4 = (long)n * NCH / 4;
    int nblocks = (int)((total4 + 255) / 256);
    bn_relu_kernel<<<nblocks, 256, 0, stream>>>(h3, hout, stats, gamma, beta, n);
}

// Round 12
// 386.047 us; speedup vs baseline: 1.0674x; 1.0480x over previous
//
#include <hip/hip_runtime.h>

#define NCH 32

typedef __attribute__((ext_vector_type(8))) __bf16 bf16x8;
typedef __attribute__((ext_vector_type(4))) float  f32x4;

union bcast16 { int4 i; bf16x8 h; };

// Split 8 fp32 values into bf16 hi + bf16 lo (residual) fragments.
// ah*bh + al*bh + ah*bl reconstructs the fp32 product to ~2^-16 relative.
static __device__ __forceinline__ void split8(const float* x, bf16x8& hi, bf16x8& lo)
{
#pragma unroll
    for (int e = 0; e < 8; ++e) {
        __bf16 h = (__bf16)x[e];
        hi[e] = h;
        lo[e] = (__bf16)(x[e] - (float)h);
    }
}

// mask-scale 8 fp32 (two f32x4) and split into bf16 hi/lo
static __device__ __forceinline__ void split8m(
    const f32x4& x0, const f32x4& x1, float m, bf16x8& hi, bf16x8& lo)
{
    float x[8] = {x0.x * m, x0.y * m, x0.z * m, x0.w * m,
                  x1.x * m, x1.y * m, x1.z * m, x1.w * m};
#pragma unroll
    for (int e = 0; e < 8; ++e) {
        __bf16 h = (__bf16)x[e];
        hi[e] = h;
        lo[e] = (__bf16)(x[e] - (float)h);
    }
}

static __device__ __forceinline__ void mfma3(
    const bf16x8& ah, const bf16x8& al,
    const bf16x8& wh, const bf16x8& wl, f32x4& acc)
{
    acc = __builtin_amdgcn_mfma_f32_16x16x32_bf16(ah, wh, acc, 0, 0, 0);
    acc = __builtin_amdgcn_mfma_f32_16x16x32_bf16(al, wh, acc, 0, 0, 0);
    acc = __builtin_amdgcn_mfma_f32_16x16x32_bf16(ah, wl, acc, 0, 0, 0);
}

static __device__ __forceinline__ ushort f2bf(float x)
{
    __bf16 b = (__bf16)x;
    return *(const ushort*)&b;
}

// Factorized 1D sparse conv as MFMA GEMM over 16-point tiles.
// ROUND-12 single change vs the 404µs champion: BRANCH-FREE taps.
// The old `if(__any(v))` guards forced idx-load -> full vmcnt drain ->
// branch -> gather -> drain per tap (~3 serialized memory latencies per
// iteration, taps' chains never overlapped). Now: all loads (idx0, idx2,
// own row, both clamped gathers) are issued at the top of the iteration;
// invalid lanes are operand-zeroed; MFMAs run center-first so the own-row
// matrix work overlaps the gathers' flight. Extra work on all-invalid
// tap-tiles is ~8 MFMAs (MFMA pipe 4% busy) and row-0 broadcast reads.
// IN_BF16:  input rows bf16 [n][32]; A fragment = one 16B load, no split.
// !IN_BF16: input rows fp32 (nt-loaded; read exactly once).
// OUT_BF16: store accumulators as bf16 (RNE); else fp32.
// Full tiles stage the 16x32 bf16 C-tile through per-wave LDS -> one
// coalesced 16B store per lane (round-11 path, kept).
// ZERO_STATS: block 0 zeroes stats[64] at kernel start.
// A fragment: lane holds f[row = tb + (lane&15)][c0..c0+7], c0=(lane>>4)*8.
// B fragments (3 taps x 2 halves, hi/lo = fp32-exact weights) in registers.
// C/D: out[tb + (lane>>4)*4 + r][(lane&15) + 16*half].
// Tap 1 is the identity map (offset 0) -> own row, no index load.
// DO_STATS: fused per-channel sum/sumsq, shuffle+LDS combine, 64 atomics/blk.
template<int IN_BF16, int OUT_BF16, int DO_STATS, int ZERO_STATS>
__global__ __launch_bounds__(256) void conv_mfma_kernel(
    const void* __restrict__ fin, const float* __restrict__ W,
    const int* __restrict__ idx, void* __restrict__ outv, int n,
    float* __restrict__ stats)
{
    __shared__ float red[4][4][16];
    __shared__ ushort ctile[4][16][NCH];   // per-wave 1KB C staging

    if constexpr (ZERO_STATS) {
        if (blockIdx.x == 0 && threadIdx.x < 2 * NCH) stats[threadIdx.x] = 0.f;
    }

    const int lane = threadIdx.x & 63;
    const int wv   = threadIdx.x >> 6;
    const int r16  = lane & 15;
    const int g    = lane >> 4;
    const int c0   = g * 8;

    const float*  ff = (const float*)fin;
    const ushort* fb = (const ushort*)fin;
    float*  of = (float*)outv;
    ushort* ob = (ushort*)outv;

    // B fragments: 3 taps x 2 output halves, hi/lo split (held in VGPRs).
    bf16x8 bh[3][2], bl[3][2];
#pragma unroll
    for (int k = 0; k < 3; ++k) {
#pragma unroll
        for (int h = 0; h < 2; ++h) {
            float w8[8];
#pragma unroll
            for (int e = 0; e < 8; ++e)
                w8[e] = W[k * NCH * NCH + (c0 + e) * NCH + (h * 16 + r16)];
            split8(w8, bh[k][h], bl[k][h]);
        }
    }

    const int ntiles = (n + 15) >> 4;
    const int nw = gridDim.x * 4;
    float s0 = 0.f, q0 = 0.f, s1 = 0.f, q1 = 0.f;

    for (int tile = blockIdx.x * 4 + wv; tile < ntiles; tile += nw) {
        const int  tb  = tile << 4;
        const int  p   = tb + r16;
        const bool pin = (p < n);
        const int  pc  = pin ? p : 0;

        // ---- issue BOTH idx loads immediately (coalesced) ----
        int i0 = idx[pc];
        int i2 = idx[2 * (size_t)n + pc];
        const bool v0 = pin && (i0 < n);
        const bool v2 = pin && (i2 < n);

        f32x4 a0 = {0.f, 0.f, 0.f, 0.f};
        f32x4 a1 = {0.f, 0.f, 0.f, 0.f};

        if constexpr (IN_BF16) {
            // ---- all three row loads in flight together ----
            int4 rawc = *(const int4*)(fb + (size_t)pc * NCH + c0);
            int4 raw0 = *(const int4*)(fb + (size_t)(v0 ? i0 : 0) * NCH + c0);
            int4 raw2 = *(const int4*)(fb + (size_t)(v2 ? i2 : 0) * NCH + c0);

            // center first (returns first; MFMAs overlap gather flight)
            if (!pin) { rawc.x = 0; rawc.y = 0; rawc.z = 0; rawc.w = 0; }
            bcast16 uc; uc.i = rawc;
            a0 = __builtin_amdgcn_mfma_f32_16x16x32_bf16(uc.h, bh[1][0], a0, 0, 0, 0);
            a0 = __builtin_amdgcn_mfma_f32_16x16x32_bf16(uc.h, bl[1][0], a0, 0, 0, 0);
            a1 = __builtin_amdgcn_mfma_f32_16x16x32_bf16(uc.h, bh[1][1], a1, 0, 0, 0);
            a1 = __builtin_amdgcn_mfma_f32_16x16x32_bf16(uc.h, bl[1][1], a1, 0, 0, 0);

            if (!v0) { raw0.x = 0; raw0.y = 0; raw0.z = 0; raw0.w = 0; }
            bcast16 u0; u0.i = raw0;
            a0 = __builtin_amdgcn_mfma_f32_16x16x32_bf16(u0.h, bh[0][0], a0, 0, 0, 0);
            a0 = __builtin_amdgcn_mfma_f32_16x16x32_bf16(u0.h, bl[0][0], a0, 0, 0, 0);
            a1 = __builtin_amdgcn_mfma_f32_16x16x32_bf16(u0.h, bh[0][1], a1, 0, 0, 0);
            a1 = __builtin_amdgcn_mfma_f32_16x16x32_bf16(u0.h, bl[0][1], a1, 0, 0, 0);

            if (!v2) { raw2.x = 0; raw2.y = 0; raw2.z = 0; raw2.w = 0; }
            bcast16 u2; u2.i = raw2;
            a0 = __builtin_amdgcn_mfma_f32_16x16x32_bf16(u2.h, bh[2][0], a0, 0, 0, 0);
            a0 = __builtin_amdgcn_mfma_f32_16x16x32_bf16(u2.h, bl[2][0], a0, 0, 0, 0);
            a1 = __builtin_amdgcn_mfma_f32_16x16x32_bf16(u2.h, bh[2][1], a1, 0, 0, 0);
            a1 = __builtin_amdgcn_mfma_f32_16x16x32_bf16(u2.h, bl[2][1], a1, 0, 0, 0);
        } else {
            const f32x4* rpc = (const f32x4*)(ff + (size_t)pc * NCH + c0);
            f32x4 xc0 = __builtin_nontemporal_load(rpc);
            f32x4 xc1 = __builtin_nontemporal_load(rpc + 1);
            const f32x4* rp0 = (const f32x4*)(ff + (size_t)(v0 ? i0 : 0) * NCH + c0);
            f32x4 x00 = __builtin_nontemporal_load(rp0);
            f32x4 x01 = __builtin_nontemporal_load(rp0 + 1);
            const f32x4* rp2 = (const f32x4*)(ff + (size_t)(v2 ? i2 : 0) * NCH + c0);
            f32x4 x20 = __builtin_nontemporal_load(rp2);
            f32x4 x21 = __builtin_nontemporal_load(rp2 + 1);

            bf16x8 ah, al;
            split8m(xc0, xc1, pin ? 1.f : 0.f, ah, al);
            mfma3(ah, al, bh[1][0], bl[1][0], a0);
            mfma3(ah, al, bh[1][1], bl[1][1], a1);
            split8m(x00, x01, v0 ? 1.f : 0.f, ah, al);
            mfma3(ah, al, bh[0][0], bl[0][0], a0);
            mfma3(ah, al, bh[0][1], bl[0][1], a1);
            split8m(x20, x21, v2 ? 1.f : 0.f, ah, al);
            mfma3(ah, al, bh[2][0], bl[2][0], a0);
            mfma3(ah, al, bh[2][1], bl[2][1], a1);
        }

        // ---- store C ----
        if (OUT_BF16 && tb + 16 <= n) {
            // full tile: stage through per-wave LDS, one 16B store per lane
#pragma unroll
            for (int r = 0; r < 4; ++r) {
                ctile[wv][g * 4 + r][r16]      = f2bf(a0[r]);
                ctile[wv][g * 4 + r][r16 + 16] = f2bf(a1[r]);
            }
            uint4 rowv = *(const uint4*)((const char*)&ctile[wv][0][0] + lane * 16);
            *(uint4*)(ob + (size_t)tb * NCH + lane * 8) = rowv;
        } else {
#pragma unroll
            for (int r = 0; r < 4; ++r) {
                int prow = tb + g * 4 + r;
                if (prow < n) {
                    if constexpr (OUT_BF16) {
                        ushort* o = ob + (size_t)prow * NCH + r16;
                        o[0]  = f2bf(a0[r]);
                        o[16] = f2bf(a1[r]);
                    } else {
                        float* o = of + (size_t)prow * NCH + r16;
                        o[0]  = a0[r];
                        o[16] = a1[r];
                    }
                }
            }
        }

        if constexpr (DO_STATS) {
#pragma unroll
            for (int r = 0; r < 4; ++r) {
                s0 += a0[r]; q0 = fmaf(a0[r], a0[r], q0);
                s1 += a1[r]; q1 = fmaf(a1[r], a1[r], q1);
            }
        }
    }

    if constexpr (DO_STATS) {
        // lanes with the same (lane&15) hold the same channel: xor-16/32 reduce
        s0 += __shfl_xor(s0, 16); s0 += __shfl_xor(s0, 32);
        q0 += __shfl_xor(q0, 16); q0 += __shfl_xor(q0, 32);
        s1 += __shfl_xor(s1, 16); s1 += __shfl_xor(s1, 32);
        q1 += __shfl_xor(q1, 16); q1 += __shfl_xor(q1, 32);
        if (lane < 16) {
            red[wv][0][r16] = s0;
            red[wv][1][r16] = q0;
            red[wv][2][r16] = s1;
            red[wv][3][r16] = q1;
        }
        __syncthreads();
        if (threadIdx.x < 64) {
            int vsel = threadIdx.x >> 4;   // 0:sum lo, 1:sq lo, 2:sum hi, 3:sq hi
            int ch   = threadIdx.x & 15;
            float t = red[0][vsel][ch] + red[1][vsel][ch] +
                      red[2][vsel][ch] + red[3][vsel][ch];
            int channel = (vsel & 2) ? (ch + 16) : ch;
            atomicAdd(stats + ((vsel & 1) ? NCH : 0) + channel, t);
        }
    }
}

// BatchNorm (batch stats) + ReLU: read bf16 h3 [n,32], write fp32 out [n,32].
__global__ __launch_bounds__(256) void bn_relu_kernel(
    const ushort* __restrict__ h3, float* __restrict__ out,
    const float* __restrict__ stats,
    const float* __restrict__ gamma, const float* __restrict__ beta, int n)
{
    long tid = (long)blockIdx.x * 256 + threadIdx.x;
    long total4 = (long)n * NCH / 4;
    if (tid >= total4) return;

    int ch0 = ((int)(tid & 7)) * 4;
    float inv_n = 1.f / (float)n;

    ushort4 v = ((const ushort4*)h3)[tid];
    ushort u[4] = {v.x, v.y, v.z, v.w};
    float r[4];
#pragma unroll
    for (int j = 0; j < 4; ++j)
        r[j] = __uint_as_float(((unsigned)u[j]) << 16);

#pragma unroll
    for (int j = 0; j < 4; ++j) {
        int ch = ch0 + j;
        float mean = stats[ch] * inv_n;
        float var = stats[NCH + ch] * inv_n - mean * mean;
        float scale = gamma[ch] * rsqrtf(var + 1e-5f);
        float shift = beta[ch] - mean * scale;
        float o = fmaf(r[j], scale, shift);
        r[j] = o > 0.f ? o : 0.f;
    }
    f32x4 o4 = {r[0], r[1], r[2], r[3]};
    __builtin_nontemporal_store(o4, (f32x4*)out + tid);
}

extern "C" void kernel_launch(void* const* d_in, const int* in_sizes, int n_in,
                              void* d_out, int out_size, void* d_ws, size_t ws_size,
                              hipStream_t stream)
{
    const float* feats = (const float*)d_in[0];
    const float* W1    = (const float*)d_in[1];
    const float* W2    = (const float*)d_in[2];
    const float* W3    = (const float*)d_in[3];
    const float* gamma = (const float*)d_in[4];
    const float* beta  = (const float*)d_in[5];
    const int*   nbr   = (const int*)d_in[6];   // [3 axes][3 taps][n]

    int n = in_sizes[0] / NCH;

    float*  hout = (float*)d_out;                     // final out (fp32)
    ushort* h1   = (ushort*)d_ws;                     // n*32 bf16; h3 reuses it
    ushort* h2   = h1 + (size_t)n * NCH;              // n*32 bf16
    ushort* h3   = h1;                                // h1 dead after conv2
    float*  stats = (float*)(h2 + (size_t)n * NCH);   // 64 floats

    const int cblocks = 2048;   // 8192 waves

    // conv1: axis 2 (z), fp32 feats (nt) -> bf16 h1; block 0 zeroes stats
    conv_mfma_kernel<0, 1, 0, 1><<<cblocks, 256, 0, stream>>>(
        feats, W1, nbr + (size_t)2 * 3 * n, h1, n, stats);
    // conv2: axis 1 (y), bf16 h1 -> bf16 h2
    conv_mfma_kernel<1, 1, 0, 0><<<cblocks, 256, 0, stream>>>(
        h1, W2, nbr + (size_t)1 * 3 * n, h2, n, stats);
    // conv3: axis 0 (x), bf16 h2 -> bf16 h3 (h1's slot), fused sum/sumsq
    conv_mfma_kernel<1, 1, 1, 0><<<cblocks, 256, 0, stream>>>(
        h2, W3, nbr + (size_t)0 * 3 * n, h3, n, stats);

    // BN + ReLU: bf16 h3 -> fp32 d_out (nt store)
    long total4 = (long)n * NCH / 4;
    int nblocks = (int)((total4 + 255) / 256);
    bn_relu_kernel<<<nblocks, 256, 0, stream>>>(h3, hout, stats, gamma, beta, n);
}